// Round 4
// baseline (818.054 us; speedup 1.0000x reference)
//
#include <hip/hip_runtime.h>
#include <cstddef>

// Problem constants (match reference)
constexpr int B = 64, T = 1024, I = 8, H = 512, O = 2;
constexpr float ALPHA = 0.2f;
constexpr float NOISE_STD = 0.05f;

constexpr int PF = 8;   // noise ring depth per batch
constexpr int NB = 2;   // batches per block (dual-recurrence interleave)

// ---------------------------------------------------------------------------
// DPP wave-64 sum reduction: result (total of all 64 lanes) lands in lane 63.
// ---------------------------------------------------------------------------
template <int CTRL>
__device__ __forceinline__ float dpp_add(float x) {
    int y = __builtin_amdgcn_update_dpp(0, __float_as_int(x), CTRL, 0xF, 0xF, true);
    return x + __int_as_float(y);
}

__device__ __forceinline__ float wave_sum_to_lane63(float x) {
    x = dpp_add<0x111>(x);  // row_shr:1
    x = dpp_add<0x112>(x);  // row_shr:2
    x = dpp_add<0x114>(x);  // row_shr:4
    x = dpp_add<0x118>(x);  // row_shr:8   -> lane 15 of each row = row sum
    x = dpp_add<0x142>(x);  // row_bcast:15
    x = dpp_add<0x143>(x);  // row_bcast:31 -> lane 63 = full sum
    return x;
}

// Fast tanh: 1 - 2/(exp(2x)+1), via v_exp_f32 + v_rcp_f32.
__device__ __forceinline__ float fast_tanh(float x) {
    float z = __builtin_amdgcn_exp2f(x * 2.885390081777927f);  // e^(2x)
    return fmaf(-2.0f, __builtin_amdgcn_rcpf(z + 1.0f), 1.0f);
}

// ---------------------------------------------------------------------------
// Dual-batch fused RNN: one 256-thread block handles TWO batches (b0, b0+1).
// 4 waves; wave w owns hidden units [w*128, w*128+128); lane l owns units
// j0 = w*128+2l, j0+1 (float2 coalesced) FOR BOTH batches.
//
// Why dual: the per-step serial overhead (s_barrier skew + ds_write/lgkm +
// post-barrier ds_read ~120cyc + DPP-tree latency) is paid ONCE per
// step-pair; the two recurrences' dependent chains interleave and fill each
// other's stalls. Same barrier protocol as before (double-buffered part[]
// slot, write -> lgkmcnt(0) -> s_barrier -> read; race-free as each slot's
// reads at step t complete before barrier(t+1), which precedes its rewrite).
//
// Key fix vs round 3: ring refills are UNCONDITIONAL (clamped address) and
// all in-loop stores are branchless (exec-masked / wrapped index), so the
// VMEM op pattern in the unrolled stream is fixed and the compiler can emit
// exact deep s_waitcnt vmcnt(N) instead of conservative per-step waits —
// rounds 1-3 all paid ~400+ cyc/step of avoidable load-latency stall there.
// ---------------------------------------------------------------------------
__global__ __launch_bounds__(256)
void rnn_dual_kernel(const float* __restrict__ input,
                     const float* __restrict__ noise,
                     const float* __restrict__ wi,
                     const float* __restrict__ si,
                     const float* __restrict__ m,
                     const float* __restrict__ n,
                     const float* __restrict__ wo,
                     const float* __restrict__ so,
                     const float* __restrict__ h0,
                     float* __restrict__ out,    // (B,T,O)
                     float* __restrict__ traj)   // (B,T,H)
{
    const int b0   = blockIdx.x * NB;
    const int w    = threadIdx.x >> 6;
    const int lane = threadIdx.x & 63;
    const int j0   = w * 128 + 2 * lane;   // first of this lane's 2 units

    __shared__ float  xin[NB * T * I];     // 64 KB: input for both batches
    __shared__ float4 part[2][NB][4];      // [buf][batch][wave] = (pa0,pa1,po0,po1)

    // ---- stage input[b0..b0+1] into LDS (contiguous, coalesced float4) ----
    {
        const float4* src = (const float4*)(input + (size_t)b0 * T * I);
        float4*       dst = (float4*)xin;
#pragma unroll
        for (int i = 0; i < (NB * T * I / 4) / 256; ++i)
            dst[threadIdx.x + 256 * i] = src[threadIdx.x + 256 * i];
    }
    __syncthreads();   // once, outside the hot loop

    constexpr float RS  = ALPHA / (float)H;
    constexpr float OMA = 1.0f - ALPHA;
    const float so0 = so[0] / (float)H;
    const float so1 = so[1] / (float)H;

    // per-lane coefficients for 2 adjacent units (shared across both batches)
    const float4 mv = *(const float4*)(m + 2 * j0);
    const float4 nv = *(const float4*)(n + 2 * j0);
    const float4 wv = *(const float4*)(wo + 2 * j0);
    const float mm0[2] = {mv.x * RS, mv.z * RS};
    const float mm1[2] = {mv.y * RS, mv.w * RS};
    const float nn0[2] = {nv.x, nv.z};
    const float nn1[2] = {nv.y, nv.w};
    const float ww0[2] = {wv.x, wv.z};
    const float ww1[2] = {wv.y, wv.w};

    float wif[I][2];
#pragma unroll
    for (int i = 0; i < I; ++i) {
        wif[i][0] = wi[i * H + j0]     * si[i];
        wif[i][1] = wi[i * H + j0 + 1] * si[i];
    }

    const float2 h0v = *(const float2*)(h0 + j0);
    float h[NB][2], r[NB][2];
#pragma unroll
    for (int q = 0; q < NB; ++q) {
        h[q][0] = h0v.x;        h[q][1] = h0v.y;
        r[q][0] = tanhf(h0v.x); r[q][1] = tanhf(h0v.y);   // full precision, once
    }

    const float* pn[NB];
    float*       pt[NB];
    float*       pout[NB];
#pragma unroll
    for (int q = 0; q < NB; ++q) {
        pn[q]   = noise + (size_t)(b0 + q) * T * H + j0;
        pt[q]   = traj  + (size_t)(b0 + q) * T * H + j0;
        pout[q] = out   + (size_t)(b0 + q) * T * O;
    }

    // ---- fill the PF-deep noise rings (statically indexed) ----
    float2 ring[NB][PF];
#pragma unroll
    for (int u = 0; u < PF; ++u)
#pragma unroll
        for (int q = 0; q < NB; ++q)
            ring[q][u] = *(const float2*)(pn[q] + (size_t)u * H);

    static_assert(T % PF == 0, "T must be a multiple of PF");

    for (int tb = 0; tb < T; tb += PF) {
#pragma unroll
        for (int u = 0; u < PF; ++u) {
            const int t  = tb + u;
            // clamped refill index: uniform s_cselect, NO branch
            const int tn = (t + PF < T) ? (t + PF) : (T - 1);

            // rank-2 + output partials for both batches (8 independent chains)
            float pa0[NB], pa1[NB], po0[NB], po1[NB];
#pragma unroll
            for (int q = 0; q < NB; ++q) {
                pa0[q] = fmaf(r[q][1], nn0[1], r[q][0] * nn0[0]);
                pa1[q] = fmaf(r[q][1], nn1[1], r[q][0] * nn1[0]);
                po0[q] = fmaf(r[q][1], ww0[1], r[q][0] * ww0[0]);
                po1[q] = fmaf(r[q][1], ww1[1], r[q][0] * ww1[0]);
            }

            // consume + UNCONDITIONALLY refill rings (exact vmcnt bookkeeping)
            float2 nz[NB];
#pragma unroll
            for (int q = 0; q < NB; ++q) {
                nz[q]      = ring[q][u];
                ring[q][u] = *(const float2*)(pn[q] + (size_t)tn * H);
            }

            // 8 interleaved DPP trees (independent -> latency overlaps)
#pragma unroll
            for (int q = 0; q < NB; ++q) {
                pa0[q] = wave_sum_to_lane63(pa0[q]);
                pa1[q] = wave_sum_to_lane63(pa1[q]);
                po0[q] = wave_sum_to_lane63(po0[q]);
                po1[q] = wave_sum_to_lane63(po1[q]);
            }

            // input projection + (1-a)h + d, off the post-barrier critical path
            float pre[NB][2];
#pragma unroll
            for (int q = 0; q < NB; ++q) {
                const float4 xa = *(const float4*)(xin + (q * T + t) * I);
                const float4 xb = *(const float4*)(xin + (q * T + t) * I + 4);
                float a0 = xa.x * wif[0][0], a1 = xa.x * wif[0][1];
                a0 = fmaf(xa.y, wif[1][0], a0); a1 = fmaf(xa.y, wif[1][1], a1);
                a0 = fmaf(xa.z, wif[2][0], a0); a1 = fmaf(xa.z, wif[2][1], a1);
                a0 = fmaf(xa.w, wif[3][0], a0); a1 = fmaf(xa.w, wif[3][1], a1);
                a0 = fmaf(xb.x, wif[4][0], a0); a1 = fmaf(xb.x, wif[4][1], a1);
                a0 = fmaf(xb.y, wif[5][0], a0); a1 = fmaf(xb.y, wif[5][1], a1);
                a0 = fmaf(xb.z, wif[6][0], a0); a1 = fmaf(xb.z, wif[6][1], a1);
                a0 = fmaf(xb.w, wif[7][0], a0); a1 = fmaf(xb.w, wif[7][1], a1);
                const float dv0 = fmaf(NOISE_STD, nz[q].x, ALPHA * a0);
                const float dv1 = fmaf(NOISE_STD, nz[q].y, ALPHA * a1);
                pre[q][0] = fmaf(h[q][0], OMA, dv0);
                pre[q][1] = fmaf(h[q][1], OMA, dv1);
            }

            if (lane == 63) {   // exec-masked, no branch
#pragma unroll
                for (int q = 0; q < NB; ++q)
                    part[t & 1][q][w] = make_float4(pa0[q], pa1[q], po0[q], po1[q]);
            }

            // raw barrier: LDS-visibility wait ONLY (vmcnt stays in flight)
            __builtin_amdgcn_sched_barrier(0);
            asm volatile("s_waitcnt lgkmcnt(0)" ::: "memory");
            __builtin_amdgcn_s_barrier();
            __builtin_amdgcn_sched_barrier(0);

#pragma unroll
            for (int q = 0; q < NB; ++q) {
                const float4 q0 = part[t & 1][q][0];
                const float4 q1 = part[t & 1][q][1];
                const float4 q2 = part[t & 1][q][2];
                const float4 q3 = part[t & 1][q][3];
                const float a0 = (q0.x + q1.x) + (q2.x + q3.x);
                const float a1 = (q0.y + q1.y) + (q2.y + q3.y);

                // out[t-1] (pre-update r). Branchless: t=0 wraps to out[T-1],
                // which the epilogue rewrites from these same threads (lane 63
                // of each wave; 4 identical redundant stores, benign).
                if (lane == 63) {
                    const float o0 = (q0.z + q1.z) + (q2.z + q3.z);
                    const float o1 = (q0.w + q1.w) + (q2.w + q3.w);
                    const int tm1 = (t + T - 1) & (T - 1);
                    *(float2*)(pout[q] + (size_t)tm1 * O) =
                        make_float2(o0 * so0, o1 * so1);
                }

                // state update + fast tanh (critical path: 2 fma + tanh)
                h[q][0] = fmaf(a1, mm1[0], fmaf(a0, mm0[0], pre[q][0]));
                h[q][1] = fmaf(a1, mm1[1], fmaf(a0, mm0[1], pre[q][1]));
                r[q][0] = fast_tanh(h[q][0]);
                r[q][1] = fast_tanh(h[q][1]);

                *(float2*)(pt[q] + (size_t)t * H) = make_float2(h[q][0], h[q][1]);
            }
        }
    }

    // ---- final output for t = T-1 (uses post-update r) ----
    {
        float p0[NB], p1[NB];
#pragma unroll
        for (int q = 0; q < NB; ++q) {
            p0[q] = fmaf(r[q][1], ww0[1], r[q][0] * ww0[0]);
            p1[q] = fmaf(r[q][1], ww1[1], r[q][0] * ww1[0]);
            p0[q] = wave_sum_to_lane63(p0[q]);
            p1[q] = wave_sum_to_lane63(p1[q]);
        }
        // Safe to reuse part[0]: its last in-loop read (t=T-2) completed
        // before barrier(T-1), which precedes this write.
        if (lane == 63) {
#pragma unroll
            for (int q = 0; q < NB; ++q)
                part[0][q][w] = make_float4(p0[q], p1[q], 0.f, 0.f);
        }
        __syncthreads();
        if (lane == 63) {
#pragma unroll
            for (int q = 0; q < NB; ++q) {
                const float4 q0 = part[0][q][0];
                const float4 q1 = part[0][q][1];
                const float4 q2 = part[0][q][2];
                const float4 q3 = part[0][q][3];
                const float o0 = (q0.x + q1.x) + (q2.x + q3.x);
                const float o1 = (q0.y + q1.y) + (q2.y + q3.y);
                *(float2*)(pout[q] + (size_t)(T - 1) * O) =
                    make_float2(o0 * so0, o1 * so1);
            }
        }
    }
}

// ---------------------------------------------------------------------------
extern "C" void kernel_launch(void* const* d_in, const int* in_sizes, int n_in,
                              void* d_out, int out_size, void* d_ws, size_t ws_size,
                              hipStream_t stream) {
    const float* input = (const float*)d_in[0];
    const float* noise = (const float*)d_in[1];
    const float* wi    = (const float*)d_in[2];
    const float* si    = (const float*)d_in[3];
    const float* m     = (const float*)d_in[4];
    const float* n     = (const float*)d_in[5];
    const float* wo    = (const float*)d_in[6];
    const float* so    = (const float*)d_in[7];
    const float* h0    = (const float*)d_in[8];

    float* out  = (float*)d_out;                       // (B,T,O) first
    float* traj = (float*)d_out + (size_t)B * T * O;   // then (B,T,H)

    (void)d_ws; (void)ws_size;

    // Single fused kernel: 32 blocks x 256 threads, 2 batches per block.
    rnn_dual_kernel<<<B / NB, 256, 0, stream>>>(input, noise, wi, si,
                                                m, n, wo, so, h0, out, traj);
}

// Round 5
// 557.813 us; speedup vs baseline: 1.4665x; 1.4665x over previous
//
#include <hip/hip_runtime.h>
#include <cstddef>

// Problem constants (match reference)
constexpr int B = 64, T = 1024, I = 8, H = 512, O = 2;
constexpr float ALPHA = 0.2f;
constexpr float NOISE_STD = 0.05f;

// Ring depth for the noise software pipeline (float2 per lane per step).
constexpr int PF = 8;

// ---------------------------------------------------------------------------
// DPP wave-64 sum reduction: result (total of all 64 lanes) lands in lane 63.
// ---------------------------------------------------------------------------
template <int CTRL>
__device__ __forceinline__ float dpp_add(float x) {
    int y = __builtin_amdgcn_update_dpp(0, __float_as_int(x), CTRL, 0xF, 0xF, true);
    return x + __int_as_float(y);
}

__device__ __forceinline__ float wave_sum_to_lane63(float x) {
    x = dpp_add<0x111>(x);  // row_shr:1
    x = dpp_add<0x112>(x);  // row_shr:2
    x = dpp_add<0x114>(x);  // row_shr:4
    x = dpp_add<0x118>(x);  // row_shr:8   -> lane 15 of each row = row sum
    x = dpp_add<0x142>(x);  // row_bcast:15
    x = dpp_add<0x143>(x);  // row_bcast:31 -> lane 63 = full sum
    return x;
}

// Fast tanh: 1 - 2/(exp(2x)+1), via v_exp_f32 + v_rcp_f32.
__device__ __forceinline__ float fast_tanh(float x) {
    float z = __builtin_amdgcn_exp2f(x * 2.885390081777927f);  // e^(2x)
    return fmaf(-2.0f, __builtin_amdgcn_rcpf(z + 1.0f), 1.0f);
}

// ---------------------------------------------------------------------------
// Fully fused RNN: one 256-thread block per batch, 4 waves, wave w owns
// hidden units [w*128, w*128+128), lane l owns units j0 = w*128+2l, j0+1.
//
// R5 change (ONE theory, two expressions of it): the in-loop VMEM op
// pattern is made STATICALLY COUNTABLE so the compiler can emit exact deep
// s_waitcnt vmcnt(N) for the PF-deep ring instead of conservative
// near-drain waits (the ~500 cyc/step tax measured in R1-R3):
//   1. ring refill is UNCONDITIONAL with a clamped uniform address
//      (s_cselect, no branch, load always issued);
//   2. the out-store is branchless: exec-masked lane==63 (all 4 waves,
//      identical values), wrapped index (t-1)&(T-1). The t=0 wrap writes a
//      stale value to out[T-1]; each wave's epilogue store to out[T-1]
//      follows ITS OWN stale store in program order, so the final memory
//      value is correct under any cross-wave interleaving.
//
// Barrier protocol unchanged: double-buffered part[] slot, ds_write ->
// lgkmcnt(0) -> s_barrier -> ds_read; vmcnt is never drained in the loop.
// ---------------------------------------------------------------------------
__global__ __launch_bounds__(256)
void rnn_fused4_kernel(const float* __restrict__ input,
                       const float* __restrict__ noise,
                       const float* __restrict__ wi,
                       const float* __restrict__ si,
                       const float* __restrict__ m,
                       const float* __restrict__ n,
                       const float* __restrict__ wo,
                       const float* __restrict__ so,
                       const float* __restrict__ h0,
                       float* __restrict__ out,    // (B,T,O)
                       float* __restrict__ traj)   // (B,T,H)
{
    const int b    = blockIdx.x;
    const int w    = threadIdx.x >> 6;
    const int lane = threadIdx.x & 63;
    const int j0   = w * 128 + 2 * lane;   // first of this lane's 2 units

    __shared__ float  xin[T * I];          // 32 KB: input[b], staged once
    __shared__ float4 part[2][4];          // [t&1][wave] = (pa0,pa1,po0,po1)

    // ---- stage input[b] into LDS (coalesced float4) ----
    {
        const float4* src = (const float4*)(input + (size_t)b * T * I);
        float4*       dst = (float4*)xin;
#pragma unroll
        for (int i = 0; i < (T * I / 4) / 256; ++i)
            dst[threadIdx.x + 256 * i] = src[threadIdx.x + 256 * i];
    }
    __syncthreads();   // once, outside the hot loop — vmcnt drain is fine here

    constexpr float RS  = ALPHA / (float)H;
    constexpr float OMA = 1.0f - ALPHA;
    const float so0 = so[0] / (float)H;
    const float so1 = so[1] / (float)H;

    // per-lane coefficients for 2 adjacent units (rows 2j0..2j0+3, 16B aligned)
    const float4 mv = *(const float4*)(m + 2 * j0);
    const float4 nv = *(const float4*)(n + 2 * j0);
    const float4 wv = *(const float4*)(wo + 2 * j0);
    const float mm0[2] = {mv.x * RS, mv.z * RS};
    const float mm1[2] = {mv.y * RS, mv.w * RS};
    const float nn0[2] = {nv.x, nv.z};
    const float nn1[2] = {nv.y, nv.w};
    const float ww0[2] = {wv.x, wv.z};
    const float ww1[2] = {wv.y, wv.w};

    float wif[I][2];
#pragma unroll
    for (int i = 0; i < I; ++i) {
        wif[i][0] = wi[i * H + j0]     * si[i];
        wif[i][1] = wi[i * H + j0 + 1] * si[i];
    }

    const float2 h0v = *(const float2*)(h0 + j0);
    float h[2] = {h0v.x, h0v.y};
    float r[2] = {tanhf(h[0]), tanhf(h[1])};   // full precision, once

    const float* pn   = noise + (size_t)b * T * H + j0;
    float*       pt   = traj  + (size_t)b * T * H + j0;
    float*       pout = out   + (size_t)b * T * O;

    // ---- fill the PF-deep noise register ring (statically indexed) ----
    float2 ring[PF];
#pragma unroll
    for (int u = 0; u < PF; ++u) ring[u] = *(const float2*)(pn + (size_t)u * H);

    static_assert(T % PF == 0, "T must be a multiple of PF");

    for (int tb = 0; tb < T; tb += PF) {
#pragma unroll
        for (int u = 0; u < PF; ++u) {
            const int t  = tb + u;
            // clamped refill index: uniform s_cselect, NO branch
            const int tn = (t + PF < T) ? (t + PF) : (T - 1);

            // uniform broadcast read of this step's 8 input values
            const float4 xa = *(const float4*)(xin + t * I);
            const float4 xb = *(const float4*)(xin + t * I + 4);

            // rank-2 + output partials from current r (4 independent 2-fma chains)
            float pa0 = fmaf(r[1], nn0[1], r[0] * nn0[0]);
            float pa1 = fmaf(r[1], nn1[1], r[0] * nn1[0]);
            float po0 = fmaf(r[1], ww0[1], r[0] * ww0[0]);
            float po1 = fmaf(r[1], ww1[1], r[0] * ww1[0]);

            // consume ring slot u, UNCONDITIONALLY refill with step tn
            // (fixed VMEM pattern -> exact deep vmcnt; load stays in flight
            // across the raw barrier)
            const float2 nz = ring[u];
            ring[u] = *(const float2*)(pn + (size_t)tn * H);

            // 4 interleaved DPP trees (independent -> latency overlaps)
            pa0 = wave_sum_to_lane63(pa0);
            pa1 = wave_sum_to_lane63(pa1);
            po0 = wave_sum_to_lane63(po0);
            po1 = wave_sum_to_lane63(po1);

            // d + (1-a)h, off the post-barrier critical path
            const float x0 = xa.x, x1 = xa.y, x2 = xa.z, x3 = xa.w;
            const float x4 = xb.x, x5 = xb.y, x6 = xb.z, x7 = xb.w;
            float acc0 = x0 * wif[0][0], acc1 = x0 * wif[0][1];
            acc0 = fmaf(x1, wif[1][0], acc0); acc1 = fmaf(x1, wif[1][1], acc1);
            acc0 = fmaf(x2, wif[2][0], acc0); acc1 = fmaf(x2, wif[2][1], acc1);
            acc0 = fmaf(x3, wif[3][0], acc0); acc1 = fmaf(x3, wif[3][1], acc1);
            acc0 = fmaf(x4, wif[4][0], acc0); acc1 = fmaf(x4, wif[4][1], acc1);
            acc0 = fmaf(x5, wif[5][0], acc0); acc1 = fmaf(x5, wif[5][1], acc1);
            acc0 = fmaf(x6, wif[6][0], acc0); acc1 = fmaf(x6, wif[6][1], acc1);
            acc0 = fmaf(x7, wif[7][0], acc0); acc1 = fmaf(x7, wif[7][1], acc1);
            const float dv0 = fmaf(NOISE_STD, nz.x, ALPHA * acc0);
            const float dv1 = fmaf(NOISE_STD, nz.y, ALPHA * acc1);
            const float pre0 = fmaf(h[0], OMA, dv0);
            const float pre1 = fmaf(h[1], OMA, dv1);

            if (lane == 63) part[t & 1][w] = make_float4(pa0, pa1, po0, po1);

            // raw barrier: LDS-visibility wait ONLY (no vmcnt drain)
            __builtin_amdgcn_sched_barrier(0);
            asm volatile("s_waitcnt lgkmcnt(0)" ::: "memory");
            __builtin_amdgcn_s_barrier();
            __builtin_amdgcn_sched_barrier(0);

            // broadcast-read the 4 wave partials
            const float4 q0 = part[t & 1][0];
            const float4 q1 = part[t & 1][1];
            const float4 q2 = part[t & 1][2];
            const float4 q3 = part[t & 1][3];
            const float a0 = (q0.x + q1.x) + (q2.x + q3.x);
            const float a1 = (q0.y + q1.y) + (q2.y + q3.y);

            // out[t-1] (pre-update r). Branchless: exec-masked lane==63 on
            // all 4 waves (identical values); t=0 wraps to out[T-1], later
            // overwritten by each wave's own epilogue store (ordered).
            if (lane == 63) {
                const float o0 = (q0.z + q1.z) + (q2.z + q3.z);
                const float o1 = (q0.w + q1.w) + (q2.w + q3.w);
                const int tm1 = (t + T - 1) & (T - 1);
                *(float2*)(pout + (size_t)tm1 * O) =
                    make_float2(o0 * so0, o1 * so1);
            }

            // state update + fast tanh (critical path: 2 fma + tanh)
            h[0] = fmaf(a1, mm1[0], fmaf(a0, mm0[0], pre0));
            h[1] = fmaf(a1, mm1[1], fmaf(a0, mm0[1], pre1));
            r[0] = fast_tanh(h[0]);
            r[1] = fast_tanh(h[1]);

            *(float2*)(pt + (size_t)t * H) = make_float2(h[0], h[1]);
        }
    }

    // ---- final output for t = T-1 (uses post-update r) ----
    {
        float po0 = fmaf(r[1], ww0[1], r[0] * ww0[0]);
        float po1 = fmaf(r[1], ww1[1], r[0] * ww1[0]);
        po0 = wave_sum_to_lane63(po0);
        po1 = wave_sum_to_lane63(po1);
        // Safe to reuse part[0]: every in-loop read of part[0] (last at
        // t=T-2) completed before barrier(T-1), which precedes this write.
        if (lane == 63) part[0][w] = make_float4(po0, po1, 0.f, 0.f);
        __syncthreads();
        // lane63 of EVERY wave stores the final value: each wave's stale
        // t=0 wrap-store to out[T-1] is ordered before this one (same wave,
        // same address), so the last writer globally is a correct store.
        if (lane == 63) {
            const float4 q0 = part[0][0];
            const float4 q1 = part[0][1];
            const float4 q2 = part[0][2];
            const float4 q3 = part[0][3];
            const float o0 = (q0.x + q1.x) + (q2.x + q3.x);
            const float o1 = (q0.y + q1.y) + (q2.y + q3.y);
            *(float2*)(pout + (size_t)(T - 1) * O) =
                make_float2(o0 * so0, o1 * so1);
        }
    }
}

// ---------------------------------------------------------------------------
extern "C" void kernel_launch(void* const* d_in, const int* in_sizes, int n_in,
                              void* d_out, int out_size, void* d_ws, size_t ws_size,
                              hipStream_t stream) {
    const float* input = (const float*)d_in[0];
    const float* noise = (const float*)d_in[1];
    const float* wi    = (const float*)d_in[2];
    const float* si    = (const float*)d_in[3];
    const float* m     = (const float*)d_in[4];
    const float* n     = (const float*)d_in[5];
    const float* wo    = (const float*)d_in[6];
    const float* so    = (const float*)d_in[7];
    const float* h0    = (const float*)d_in[8];

    float* out  = (float*)d_out;                       // (B,T,O) first
    float* traj = (float*)d_out + (size_t)B * T * O;   // then (B,T,H)

    (void)d_ws; (void)ws_size;

    // Single fully fused kernel: 64 blocks x 256 threads (4 waves/batch).
    rnn_fused4_kernel<<<B, 256, 0, stream>>>(input, noise, wi, si,
                                             m, n, wo, so, h0, out, traj);
}